// Round 3
// baseline (636.751 us; speedup 1.0000x reference)
//
#include <hip/hip_runtime.h>
#include <cstdint>

#define KDIM 4096
#define NNODE 4096

typedef __bf16 bf16x8 __attribute__((ext_vector_type(8)));
typedef float floatx4 __attribute__((ext_vector_type(4)));

__device__ __forceinline__ uint16_t f2b(float f) {
  union { float f; uint32_t u; } v; v.f = f;
  uint32_t u = v.u;
  return (uint16_t)((u + 0x7FFFu + ((u >> 16) & 1u)) >> 16);  // RNE
}
__device__ __forceinline__ float b2f(uint16_t h) {
  union { uint32_t u; float f; } v; v.u = ((uint32_t)h) << 16; return v.f;
}

// ---------- fp32 -> bf16 conversion of both supports ----------
__global__ __launch_bounds__(256) void cvt_supports(
    const float* __restrict__ s0, const float* __restrict__ s1,
    uint16_t* __restrict__ d0, uint16_t* __restrict__ d1) {
  const float* src = blockIdx.y ? s1 : s0;
  uint16_t* dst = blockIdx.y ? d1 : d0;
  size_t i = ((size_t)blockIdx.x * 256 + threadIdx.x) * 4;
  float4 v = *(const float4*)(src + i);
  ushort4 o;
  o.x = f2b(v.x); o.y = f2b(v.y); o.z = f2b(v.z); o.w = f2b(v.w);
  *(ushort4*)(dst + i) = o;
}

// ---------- pack A-operand for GEMM1: rows = (b, [feats(2); prev(16)]) ----------
__global__ __launch_bounds__(256) void pack_x1(
    const float* __restrict__ inp, const float* __restrict__ st,
    uint16_t* __restrict__ X1) {
  size_t e = ((size_t)blockIdx.x * 256 + threadIdx.x) * 4;  // elem in (1152,4096)
  int r = (int)(e >> 12), n = (int)(e & 4095);
  int b = r / 18, c = r - b * 18;
  const float* src = (c < 2) ? (inp + (size_t)b * 8192 + (size_t)c * 4096 + n)
                             : (st + (size_t)b * 65536 + (size_t)(c - 2) * 4096 + n);
  float4 v = *(const float4*)src;
  ushort4 o;
  o.x = f2b(v.x); o.y = f2b(v.y); o.z = f2b(v.z); o.w = f2b(v.w);
  *(ushort4*)(X1 + e) = o;
}

// ---------- bf16 GEMM: C = A * S^T, S row-major (out[row,m]=sum_k A[row,k]S[m,k])
// 128(row) x 64(col) tile, BK=32, 256 threads (4 waves in 2x2), 16x16x32 MFMA.
// Tile shrunk from 128x128 to raise block count (576->1152): R2 showed the GEMMs
// are occupancy/latency-bound (MfmaUtil 16%, Occupancy 20%, 2.25 blocks/CU).
// LDS layout [q][m][8]: q = k-chunk (8 bf16), m = tile row/col.
template <int MODE>
__global__ __launch_bounds__(256) void gemm_bt(
    const uint16_t* __restrict__ A, const uint16_t* __restrict__ S0,
    const uint16_t* __restrict__ S1, uint16_t* __restrict__ D) {
  constexpr int CPB = (MODE == 1) ? 18 : 16;    // A channels per batch
  constexpr int OUTC = (MODE == 1) ? 36 : 32;   // output channels per batch
  __shared__ __align__(16) uint16_t lsA[128 * 32];  // 8 KB
  __shared__ __align__(16) uint16_t lsB[64 * 32];   // 4 KB
  const int tid = threadIdx.x;
  const int lane = tid & 63, wave = tid >> 6;
  const int wr = wave >> 1, wc = wave & 1;
  const int s = blockIdx.z;
  const uint16_t* __restrict__ Bm = s ? S1 : S0;
  const int rowBase = blockIdx.y * 128;
  const int colBase = blockIdx.x * 64;

  // staging per K-step: A = 512 slots (8 issues), B = 256 slots (4 issues);
  // each wave: 2 A-issues + 1 B-issue of 64 lanes x 16 B.
  const uint16_t* gA[2];
  uint32_t ldsOffA[2];
#pragma unroll
  for (int j = 0; j < 2; ++j) {
    int g = wave * 2 + j;          // 0..7
    int slot = g * 64 + lane;      // 0..511
    int q = slot >> 7, m = slot & 127;
    gA[j] = A + (size_t)(rowBase + m) * KDIM + q * 8;
    ldsOffA[j] = (uint32_t)(g * 512);  // elements; [q][m][8] contiguous in slot
  }
  const uint16_t* gB;
  uint32_t ldsOffB;
  {
    int slot = wave * 64 + lane;   // 0..255
    int q = slot >> 6, m = slot & 63;
    gB = Bm + (size_t)(colBase + m) * KDIM + q * 8;
    ldsOffB = (uint32_t)(wave * 512);
  }

  floatx4 acc[4][2];
#pragma unroll
  for (int i = 0; i < 4; ++i)
#pragma unroll
    for (int j = 0; j < 2; ++j) acc[i][j] = (floatx4){0.f, 0.f, 0.f, 0.f};

  const int q = lane >> 4, mr = lane & 15;

  for (int k0 = 0; k0 < KDIM; k0 += 32) {
    __syncthreads();  // previous compute done reading LDS
#pragma unroll
    for (int j = 0; j < 2; ++j)
      __builtin_amdgcn_global_load_lds(
          (const __attribute__((address_space(1))) uint32_t*)(gA[j] + k0),
          (__attribute__((address_space(3))) uint32_t*)(lsA + ldsOffA[j]), 16, 0, 0);
    __builtin_amdgcn_global_load_lds(
        (const __attribute__((address_space(1))) uint32_t*)(gB + k0),
        (__attribute__((address_space(3))) uint32_t*)(lsB + ldsOffB), 16, 0, 0);
    __syncthreads();  // vmcnt(0) drained: tile resident

    bf16x8 af[4], bf[2];
#pragma unroll
    for (int rt = 0; rt < 4; ++rt)
      af[rt] = *(const bf16x8*)(lsA + (q * 128 + wr * 64 + rt * 16 + mr) * 8);
#pragma unroll
    for (int ct = 0; ct < 2; ++ct)
      bf[ct] = *(const bf16x8*)(lsB + (q * 64 + wc * 32 + ct * 16 + mr) * 8);
#pragma unroll
    for (int rt = 0; rt < 4; ++rt)
#pragma unroll
      for (int ct = 0; ct < 2; ++ct)
        acc[rt][ct] = __builtin_amdgcn_mfma_f32_16x16x32_bf16(af[rt], bf[ct], acc[rt][ct], 0, 0, 0);
  }

  // epilogue: C/D layout col=lane&15, row=(lane>>4)*4+reg
#pragma unroll
  for (int rt = 0; rt < 4; ++rt) {
#pragma unroll
    for (int r = 0; r < 4; ++r) {
      int rowg = rowBase + wr * 64 + rt * 16 + (lane >> 4) * 4 + r;
      int b = rowg / CPB, c = rowg - b * CPB;
      int jj;
      if (MODE == 1) jj = (c < 2) ? (2 * s + c) : (4 + 16 * s + (c - 2));
      else jj = 16 * s + c;
      uint16_t* drow = D + (size_t)(b * OUTC + jj) * NNODE;
#pragma unroll
      for (int ct = 0; ct < 2; ++ct) {
        int colg = colBase + wc * 32 + ct * 16 + mr;
        drow[colg] = f2b(acc[rt][ct][r]);
      }
    }
  }
}

// ---------- stage2: r,u gates; X2 = r*prev (bf16), U kept fp32 ----------
__global__ __launch_bounds__(256) void stage2(
    const uint16_t* __restrict__ D1, const float* __restrict__ state,
    const float* __restrict__ rk, const float* __restrict__ uk,
    uint16_t* __restrict__ X2, float* __restrict__ U) {
  __shared__ float s_rk[576], s_uk[576];
  for (int i = threadIdx.x; i < 576; i += 256) { s_rk[i] = rk[i]; s_uk[i] = uk[i]; }
  __syncthreads();
  int idx = blockIdx.x * 256 + threadIdx.x;
  int b = idx >> 12, n = idx & 4095;
  float hs[36];
  const uint16_t* p = D1 + (size_t)b * 36 * NNODE + n;
#pragma unroll
  for (int j = 0; j < 36; ++j) hs[j] = b2f(p[(size_t)j * NNODE]);
  float ar[16], au[16];
#pragma unroll
  for (int k = 0; k < 16; ++k) { ar[k] = 0.f; au[k] = 0.f; }
#pragma unroll
  for (int j = 0; j < 36; ++j) {
    float h = hs[j];
#pragma unroll
    for (int k = 0; k < 16; ++k) {
      ar[k] += h * s_rk[j * 16 + k];
      au[k] += h * s_uk[j * 16 + k];
    }
  }
  const float* sp = state + (size_t)b * 65536 + n;
#pragma unroll
  for (int k = 0; k < 16; ++k) {
    float r = 1.f / (1.f + __expf(-ar[k]));
    float uu = 1.f / (1.f + __expf(-au[k]));
    float prev = sp[(size_t)k * NNODE];
    X2[(size_t)(b * 16 + k) * NNODE + n] = f2b(r * prev);
    U[(size_t)(b * 16 + k) * NNODE + n] = uu;
  }
}

// ---------- stage4: c = tanh([h;D3]*ck); z = u*prev + (1-u)*c ----------
// OUTPUT LAYOUT: z is (B, N, U) reshaped to (B, U*N) => out[b*65536 + n*16 + k]
__global__ __launch_bounds__(256) void stage4(
    const uint16_t* __restrict__ D1, const uint16_t* __restrict__ D3,
    const float* __restrict__ U, const float* __restrict__ state,
    const float* __restrict__ ck, float* __restrict__ out) {
  __shared__ float s_ck[576];
  for (int i = threadIdx.x; i < 576; i += 256) s_ck[i] = ck[i];
  __syncthreads();
  int idx = blockIdx.x * 256 + threadIdx.x;
  int b = idx >> 12, n = idx & 4095;
  float hv[36];
  const uint16_t* p1 = D1 + (size_t)b * 36 * NNODE + n;
#pragma unroll
  for (int j = 0; j < 4; ++j) hv[j] = b2f(p1[(size_t)j * NNODE]);
  const uint16_t* p3 = D3 + (size_t)b * 32 * NNODE + n;
#pragma unroll
  for (int j = 0; j < 32; ++j) hv[4 + j] = b2f(p3[(size_t)j * NNODE]);
  float ac[16];
#pragma unroll
  for (int k = 0; k < 16; ++k) ac[k] = 0.f;
#pragma unroll
  for (int j = 0; j < 36; ++j) {
    float h = hv[j];
#pragma unroll
    for (int k = 0; k < 16; ++k) ac[k] += h * s_ck[j * 16 + k];
  }
  const float* sp = state + (size_t)b * 65536 + n;
  const float* up = U + (size_t)b * 16 * NNODE + n;
  float z[16];
#pragma unroll
  for (int k = 0; k < 16; ++k) {
    float e = __expf(2.f * ac[k]);
    float c = 1.f - 2.f / (e + 1.f);  // tanh, saturates correctly at +/-inf
    float uu = up[(size_t)k * NNODE];
    float prev = sp[(size_t)k * NNODE];
    z[k] = uu * prev + (1.f - uu) * c;
  }
  float4* po = (float4*)(out + (size_t)b * 65536 + (size_t)n * 16);
#pragma unroll
  for (int k4 = 0; k4 < 4; ++k4)
    po[k4] = make_float4(z[k4 * 4], z[k4 * 4 + 1], z[k4 * 4 + 2], z[k4 * 4 + 3]);
}

extern "C" void kernel_launch(void* const* d_in, const int* in_sizes, int n_in,
                              void* d_out, int out_size, void* d_ws, size_t ws_size,
                              hipStream_t stream) {
  const float* inputs = (const float*)d_in[0];
  const float* state = (const float*)d_in[1];
  const float* s0 = (const float*)d_in[2];
  const float* s1 = (const float*)d_in[3];
  const float* rk = (const float*)d_in[4];
  const float* uk = (const float*)d_in[5];
  const float* ck = (const float*)d_in[6];
  float* out = (float*)d_out;
  char* ws = (char*)d_ws;

  // workspace layout (bytes)
  uint16_t* S0b = (uint16_t*)(ws);                  // 33,554,432
  uint16_t* S1b = (uint16_t*)(ws + 33554432);       // 33,554,432
  uint16_t* X1 = (uint16_t*)(ws + 67108864);        // 9,437,184   (1152 x 4096 bf16)
  uint16_t* D1 = (uint16_t*)(ws + 76546048);        // 18,874,368  (64 x 36 x 4096 bf16)
  uint16_t* X2 = (uint16_t*)(ws + 95420416);        // 8,388,608   (1024 x 4096 bf16)
  float* U = (float*)(ws + 103809024);              // 16,777,216  (64 x 16 x 4096 f32)
  uint16_t* D3 = (uint16_t*)(ws + 120586240);       // 16,777,216  (64 x 32 x 4096 bf16)
  // total 137,363,456 bytes

  cvt_supports<<<dim3(16384, 2), 256, 0, stream>>>(s0, s1, S0b, S1b);
  pack_x1<<<4608, 256, 0, stream>>>(inputs, state, X1);
  gemm_bt<1><<<dim3(64, 9, 2), 256, 0, stream>>>(X1, S0b, S1b, D1);
  stage2<<<1024, 256, 0, stream>>>(D1, state, rk, uk, X2, U);
  gemm_bt<3><<<dim3(64, 8, 2), 256, 0, stream>>>(X2, S0b, S1b, D3);
  stage4<<<1024, 256, 0, stream>>>(D1, D3, U, state, ck, out);
}

// Round 4
// 527.413 us; speedup vs baseline: 1.2073x; 1.2073x over previous
//
#include <hip/hip_runtime.h>
#include <cstdint>

#define KDIM 4096
#define NNODE 4096
#define KSPLIT 2
#define KHALF (KDIM / KSPLIT)

typedef __bf16 bf16x8 __attribute__((ext_vector_type(8)));
typedef float floatx4 __attribute__((ext_vector_type(4)));

__device__ __forceinline__ uint16_t f2b(float f) {
  union { float f; uint32_t u; } v; v.f = f;
  uint32_t u = v.u;
  return (uint16_t)((u + 0x7FFFu + ((u >> 16) & 1u)) >> 16);  // RNE
}
__device__ __forceinline__ float b2f(uint16_t h) {
  union { uint32_t u; float f; } v; v.u = ((uint32_t)h) << 16; return v.f;
}

// ---------- fp32 -> bf16 conversion of both supports ----------
__global__ __launch_bounds__(256) void cvt_supports(
    const float* __restrict__ s0, const float* __restrict__ s1,
    uint16_t* __restrict__ d0, uint16_t* __restrict__ d1) {
  const float* src = blockIdx.y ? s1 : s0;
  uint16_t* dst = blockIdx.y ? d1 : d0;
  size_t i = ((size_t)blockIdx.x * 256 + threadIdx.x) * 4;
  float4 v = *(const float4*)(src + i);
  ushort4 o;
  o.x = f2b(v.x); o.y = f2b(v.y); o.z = f2b(v.z); o.w = f2b(v.w);
  *(ushort4*)(dst + i) = o;
}

// ---------- pack A-operand for GEMM1: rows = (b, [feats(2); prev(16)]) ----------
__global__ __launch_bounds__(256) void pack_x1(
    const float* __restrict__ inp, const float* __restrict__ st,
    uint16_t* __restrict__ X1) {
  size_t e = ((size_t)blockIdx.x * 256 + threadIdx.x) * 4;  // elem in (1152,4096)
  int r = (int)(e >> 12), n = (int)(e & 4095);
  int b = r / 18, c = r - b * 18;
  const float* src = (c < 2) ? (inp + (size_t)b * 8192 + (size_t)c * 4096 + n)
                             : (st + (size_t)b * 65536 + (size_t)(c - 2) * 4096 + n);
  float4 v = *(const float4*)src;
  ushort4 o;
  o.x = f2b(v.x); o.y = f2b(v.y); o.z = f2b(v.z); o.w = f2b(v.w);
  *(ushort4*)(X1 + e) = o;
}

// ---------- bf16 GEMM: C = A * S^T, split-K, S row-major.
// 128x128 tile, BK=32, 256 threads (4 waves 2x2), 16x16x32 MFMA — R2's config
// (16 MFMA/wave/K-step; R3 showed halving this halves MfmaUtil). Split-K=2
// raises grid 576->1152 (4.5 blocks/CU, the m97/m102 833-TF regime) without
// touching per-barrier MFMA density. blockIdx.z = ks*2 + support.
// Partial (bf16) written to D + ks*pstride; consumers sum the 2 partials.
template <int MODE>
__global__ __launch_bounds__(256) void gemm_bt(
    const uint16_t* __restrict__ A, const uint16_t* __restrict__ S0,
    const uint16_t* __restrict__ S1, uint16_t* __restrict__ D) {
  constexpr int CPB = (MODE == 1) ? 18 : 16;    // A channels per batch
  constexpr int OUTC = (MODE == 1) ? 36 : 32;   // output channels per batch
  constexpr size_t PSTRIDE = (size_t)64 * OUTC * NNODE;  // partial-buffer stride
  __shared__ __align__(16) uint16_t lsA[128 * 32];
  __shared__ __align__(16) uint16_t lsB[128 * 32];
  const int tid = threadIdx.x;
  const int lane = tid & 63, wave = tid >> 6;
  const int wr = wave >> 1, wc = wave & 1;
  const int s = blockIdx.z & 1;
  const int ks = blockIdx.z >> 1;
  const uint16_t* __restrict__ Bm = s ? S1 : S0;
  const int rowBase = blockIdx.y * 128;
  const int colBase = blockIdx.x * 128;

  // staging: 512 slots of 16B per tile; wave handles 2 issues of 64 slots each
  const uint16_t* gA[2];
  const uint16_t* gB[2];
  uint32_t ldsOff[2];
#pragma unroll
  for (int j = 0; j < 2; ++j) {
    int g = wave * 2 + j;
    int slot = g * 64 + lane;
    int q = slot >> 7, m = slot & 127;
    gA[j] = A + (size_t)(rowBase + m) * KDIM + q * 8;
    gB[j] = Bm + (size_t)(colBase + m) * KDIM + q * 8;
    ldsOff[j] = (uint32_t)(g * 64 * 8);  // wave-uniform LDS base (elements)
  }

  floatx4 acc[4][4];
#pragma unroll
  for (int i = 0; i < 4; ++i)
#pragma unroll
    for (int j = 0; j < 4; ++j) acc[i][j] = (floatx4){0.f, 0.f, 0.f, 0.f};

  const int q = lane >> 4, mr = lane & 15;

  const int kBeg = ks * KHALF, kEnd = kBeg + KHALF;
  for (int k0 = kBeg; k0 < kEnd; k0 += 32) {
    __syncthreads();  // previous compute done reading LDS
#pragma unroll
    for (int j = 0; j < 2; ++j) {
      __builtin_amdgcn_global_load_lds(
          (const __attribute__((address_space(1))) uint32_t*)(gA[j] + k0),
          (__attribute__((address_space(3))) uint32_t*)(lsA + ldsOff[j]), 16, 0, 0);
      __builtin_amdgcn_global_load_lds(
          (const __attribute__((address_space(1))) uint32_t*)(gB[j] + k0),
          (__attribute__((address_space(3))) uint32_t*)(lsB + ldsOff[j]), 16, 0, 0);
    }
    __syncthreads();  // vmcnt(0) drained: tile resident

    bf16x8 af[4], bf[4];
#pragma unroll
    for (int rt = 0; rt < 4; ++rt)
      af[rt] = *(const bf16x8*)(lsA + (q * 128 + wr * 64 + rt * 16 + mr) * 8);
#pragma unroll
    for (int ct = 0; ct < 4; ++ct)
      bf[ct] = *(const bf16x8*)(lsB + (q * 128 + wc * 64 + ct * 16 + mr) * 8);
#pragma unroll
    for (int rt = 0; rt < 4; ++rt)
#pragma unroll
      for (int ct = 0; ct < 4; ++ct)
        acc[rt][ct] = __builtin_amdgcn_mfma_f32_16x16x32_bf16(af[rt], bf[ct], acc[rt][ct], 0, 0, 0);
  }

  uint16_t* Dp = D + (size_t)ks * PSTRIDE;
  // epilogue: C/D layout col=lane&15, row=(lane>>4)*4+reg
#pragma unroll
  for (int rt = 0; rt < 4; ++rt) {
#pragma unroll
    for (int r = 0; r < 4; ++r) {
      int rowg = rowBase + wr * 64 + rt * 16 + (lane >> 4) * 4 + r;
      int b = rowg / CPB, c = rowg - b * CPB;
      int jj;
      if (MODE == 1) jj = (c < 2) ? (2 * s + c) : (4 + 16 * s + (c - 2));
      else jj = 16 * s + c;
      uint16_t* drow = Dp + (size_t)(b * OUTC + jj) * NNODE;
#pragma unroll
      for (int ct = 0; ct < 4; ++ct) {
        int colg = colBase + wc * 64 + ct * 16 + mr;
        drow[colg] = f2b(acc[rt][ct][r]);
      }
    }
  }
}

// ---------- stage2: r,u gates; X2 = r*prev (bf16), U kept fp32 ----------
__global__ __launch_bounds__(256) void stage2(
    const uint16_t* __restrict__ P1, const float* __restrict__ state,
    const float* __restrict__ rk, const float* __restrict__ uk,
    uint16_t* __restrict__ X2, float* __restrict__ U) {
  constexpr size_t PS = (size_t)64 * 36 * NNODE;
  __shared__ float s_rk[576], s_uk[576];
  for (int i = threadIdx.x; i < 576; i += 256) { s_rk[i] = rk[i]; s_uk[i] = uk[i]; }
  __syncthreads();
  int idx = blockIdx.x * 256 + threadIdx.x;
  int b = idx >> 12, n = idx & 4095;
  float hs[36];
  const uint16_t* p = P1 + (size_t)b * 36 * NNODE + n;
#pragma unroll
  for (int j = 0; j < 36; ++j)
    hs[j] = b2f(p[(size_t)j * NNODE]) + b2f(p[PS + (size_t)j * NNODE]);
  float ar[16], au[16];
#pragma unroll
  for (int k = 0; k < 16; ++k) { ar[k] = 0.f; au[k] = 0.f; }
#pragma unroll
  for (int j = 0; j < 36; ++j) {
    float h = hs[j];
#pragma unroll
    for (int k = 0; k < 16; ++k) {
      ar[k] += h * s_rk[j * 16 + k];
      au[k] += h * s_uk[j * 16 + k];
    }
  }
  const float* sp = state + (size_t)b * 65536 + n;
#pragma unroll
  for (int k = 0; k < 16; ++k) {
    float r = 1.f / (1.f + __expf(-ar[k]));
    float uu = 1.f / (1.f + __expf(-au[k]));
    float prev = sp[(size_t)k * NNODE];
    X2[(size_t)(b * 16 + k) * NNODE + n] = f2b(r * prev);
    U[(size_t)(b * 16 + k) * NNODE + n] = uu;
  }
}

// ---------- stage4: c = tanh([h;D3]*ck); z = u*prev + (1-u)*c ----------
// OUTPUT LAYOUT: z is (B, N, U) reshaped to (B, U*N) => out[b*65536 + n*16 + k]
__global__ __launch_bounds__(256) void stage4(
    const uint16_t* __restrict__ P1, const uint16_t* __restrict__ P3,
    const float* __restrict__ U, const float* __restrict__ state,
    const float* __restrict__ ck, float* __restrict__ out) {
  constexpr size_t PS1 = (size_t)64 * 36 * NNODE;
  constexpr size_t PS3 = (size_t)64 * 32 * NNODE;
  __shared__ float s_ck[576];
  for (int i = threadIdx.x; i < 576; i += 256) s_ck[i] = ck[i];
  __syncthreads();
  int idx = blockIdx.x * 256 + threadIdx.x;
  int b = idx >> 12, n = idx & 4095;
  float hv[36];
  const uint16_t* p1 = P1 + (size_t)b * 36 * NNODE + n;
#pragma unroll
  for (int j = 0; j < 4; ++j)
    hv[j] = b2f(p1[(size_t)j * NNODE]) + b2f(p1[PS1 + (size_t)j * NNODE]);
  const uint16_t* p3 = P3 + (size_t)b * 32 * NNODE + n;
#pragma unroll
  for (int j = 0; j < 32; ++j)
    hv[4 + j] = b2f(p3[(size_t)j * NNODE]) + b2f(p3[PS3 + (size_t)j * NNODE]);
  float ac[16];
#pragma unroll
  for (int k = 0; k < 16; ++k) ac[k] = 0.f;
#pragma unroll
  for (int j = 0; j < 36; ++j) {
    float h = hv[j];
#pragma unroll
    for (int k = 0; k < 16; ++k) ac[k] += h * s_ck[j * 16 + k];
  }
  const float* sp = state + (size_t)b * 65536 + n;
  const float* up = U + (size_t)b * 16 * NNODE + n;
  float z[16];
#pragma unroll
  for (int k = 0; k < 16; ++k) {
    float e = __expf(2.f * ac[k]);
    float c = 1.f - 2.f / (e + 1.f);  // tanh, saturates correctly at +/-inf
    float uu = up[(size_t)k * NNODE];
    float prev = sp[(size_t)k * NNODE];
    z[k] = uu * prev + (1.f - uu) * c;
  }
  float4* po = (float4*)(out + (size_t)b * 65536 + (size_t)n * 16);
#pragma unroll
  for (int k4 = 0; k4 < 4; ++k4)
    po[k4] = make_float4(z[k4 * 4], z[k4 * 4 + 1], z[k4 * 4 + 2], z[k4 * 4 + 3]);
}

extern "C" void kernel_launch(void* const* d_in, const int* in_sizes, int n_in,
                              void* d_out, int out_size, void* d_ws, size_t ws_size,
                              hipStream_t stream) {
  const float* inputs = (const float*)d_in[0];
  const float* state = (const float*)d_in[1];
  const float* s0 = (const float*)d_in[2];
  const float* s1 = (const float*)d_in[3];
  const float* rk = (const float*)d_in[4];
  const float* uk = (const float*)d_in[5];
  const float* ck = (const float*)d_in[6];
  float* out = (float*)d_out;
  char* ws = (char*)d_ws;

  // workspace layout (bytes); X2 aliases X1 (dead after gemm1)
  uint16_t* S0b = (uint16_t*)(ws);                  // 33,554,432
  uint16_t* S1b = (uint16_t*)(ws + 33554432);       // 33,554,432
  uint16_t* X1 = (uint16_t*)(ws + 67108864);        // 9,437,184   (1152 x 4096 bf16)
  uint16_t* X2 = (uint16_t*)(ws + 67108864);        // 8,388,608   (aliases X1)
  uint16_t* P1 = (uint16_t*)(ws + 76546048);        // 2 x 18,874,368 (split-K partials)
  float* U = (float*)(ws + 114294784);              // 16,777,216  (64 x 16 x 4096 f32)
  uint16_t* P3 = (uint16_t*)(ws + 131072000);       // 2 x 16,777,216 (split-K partials)
  // total 164,626,432 bytes

  cvt_supports<<<dim3(16384, 2), 256, 0, stream>>>(s0, s1, S0b, S1b);
  pack_x1<<<4608, 256, 0, stream>>>(inputs, state, X1);
  gemm_bt<1><<<dim3(32, 9, 2 * KSPLIT), 256, 0, stream>>>(X1, S0b, S1b, P1);
  stage2<<<1024, 256, 0, stream>>>(P1, state, rk, uk, X2, U);
  gemm_bt<3><<<dim3(32, 8, 2 * KSPLIT), 256, 0, stream>>>(X2, S0b, S1b, P3);
  stage4<<<1024, 256, 0, stream>>>(P1, P3, U, state, ck, out);
}

// Round 5
// 513.163 us; speedup vs baseline: 1.2408x; 1.0278x over previous
//
#include <hip/hip_runtime.h>
#include <cstdint>

#define KDIM 4096
#define NNODE 4096
#define KSPLIT 2
#define KHALF (KDIM / KSPLIT)

typedef __bf16 bf16x8 __attribute__((ext_vector_type(8)));
typedef float floatx4 __attribute__((ext_vector_type(4)));

__device__ __forceinline__ uint16_t f2b(float f) {
  union { float f; uint32_t u; } v; v.f = f;
  uint32_t u = v.u;
  return (uint16_t)((u + 0x7FFFu + ((u >> 16) & 1u)) >> 16);  // RNE
}
__device__ __forceinline__ float b2f(uint16_t h) {
  union { uint32_t u; float f; } v; v.u = ((uint32_t)h) << 16; return v.f;
}

// ---------- fp32 -> bf16 conversion of both supports ----------
__global__ __launch_bounds__(256) void cvt_supports(
    const float* __restrict__ s0, const float* __restrict__ s1,
    uint16_t* __restrict__ d0, uint16_t* __restrict__ d1) {
  const float* src = blockIdx.y ? s1 : s0;
  uint16_t* dst = blockIdx.y ? d1 : d0;
  size_t i = ((size_t)blockIdx.x * 256 + threadIdx.x) * 4;
  float4 v = *(const float4*)(src + i);
  ushort4 o;
  o.x = f2b(v.x); o.y = f2b(v.y); o.z = f2b(v.z); o.w = f2b(v.w);
  *(ushort4*)(dst + i) = o;
}

// ---------- pack A-operand for GEMM1: rows = (b, [feats(2); prev(16)]) ----------
__global__ __launch_bounds__(256) void pack_x1(
    const float* __restrict__ inp, const float* __restrict__ st,
    uint16_t* __restrict__ X1) {
  size_t e = ((size_t)blockIdx.x * 256 + threadIdx.x) * 4;  // elem in (1152,4096)
  int r = (int)(e >> 12), n = (int)(e & 4095);
  int b = r / 18, c = r - b * 18;
  const float* src = (c < 2) ? (inp + (size_t)b * 8192 + (size_t)c * 4096 + n)
                             : (st + (size_t)b * 65536 + (size_t)(c - 2) * 4096 + n);
  float4 v = *(const float4*)src;
  ushort4 o;
  o.x = f2b(v.x); o.y = f2b(v.y); o.z = f2b(v.z); o.w = f2b(v.w);
  *(ushort4*)(X1 + e) = o;
}

// ---------- bf16 GEMM: C = A * S^T, split-K, S row-major.
// 128x128 tile, BK=32, 4 waves 2x2, 16x16x32 MFMA, split-K=2.
// R4 diagnosis: 2-barrier K-loop costs ~855 cyc/step, ~700 of it the
// vmcnt(0)+barrier drain of global_load_lds (~500 cyc LLC latency), with only
// ~154 cyc/SIMD of MFMA. R5: single-barrier double-buffered pipeline using raw
// s_barrier + manual s_waitcnt vmcnt(0) so the NEXT tile's loads stay in
// flight across the barrier and the CUR tile's latency is overlapped by the
// previous step's compute.
template <int MODE>
__global__ __launch_bounds__(256) void gemm_bt(
    const uint16_t* __restrict__ A, const uint16_t* __restrict__ S0,
    const uint16_t* __restrict__ S1, uint16_t* __restrict__ D) {
  constexpr int CPB = (MODE == 1) ? 18 : 16;    // A channels per batch
  constexpr int OUTC = (MODE == 1) ? 36 : 32;   // output channels per batch
  constexpr size_t PSTRIDE = (size_t)64 * OUTC * NNODE;  // partial-buffer stride
  __shared__ __align__(16) uint16_t lsA[2][128 * 32];
  __shared__ __align__(16) uint16_t lsB[2][128 * 32];
  const int tid = threadIdx.x;
  const int lane = tid & 63, wave = tid >> 6;
  const int wr = wave >> 1, wc = wave & 1;
  const int s = blockIdx.z & 1;
  const int ks = blockIdx.z >> 1;
  const uint16_t* __restrict__ Bm = s ? S1 : S0;
  const int rowBase = blockIdx.y * 128;
  const int colBase = blockIdx.x * 128;

  // staging: 512 slots of 16B per tile; wave handles 2 issues of 64 slots each
  const uint16_t* gA[2];
  const uint16_t* gB[2];
  uint32_t ldsOff[2];
#pragma unroll
  for (int j = 0; j < 2; ++j) {
    int g = wave * 2 + j;
    int slot = g * 64 + lane;
    int q = slot >> 7, m = slot & 127;
    gA[j] = A + (size_t)(rowBase + m) * KDIM + q * 8;
    gB[j] = Bm + (size_t)(colBase + m) * KDIM + q * 8;
    ldsOff[j] = (uint32_t)(g * 64 * 8);  // wave-uniform LDS base (elements)
  }

  floatx4 acc[4][4];
#pragma unroll
  for (int i = 0; i < 4; ++i)
#pragma unroll
    for (int j = 0; j < 4; ++j) acc[i][j] = (floatx4){0.f, 0.f, 0.f, 0.f};

  const int q = lane >> 4, mr = lane & 15;
  const int kBeg = ks * KHALF, kEnd = kBeg + KHALF;

  // prologue: stage tile kBeg into buffer 0
#pragma unroll
  for (int j = 0; j < 2; ++j) {
    __builtin_amdgcn_global_load_lds(
        (const __attribute__((address_space(1))) uint32_t*)(gA[j] + kBeg),
        (__attribute__((address_space(3))) uint32_t*)(&lsA[0][0] + ldsOff[j]), 16, 0, 0);
    __builtin_amdgcn_global_load_lds(
        (const __attribute__((address_space(1))) uint32_t*)(gB[j] + kBeg),
        (__attribute__((address_space(3))) uint32_t*)(&lsB[0][0] + ldsOff[j]), 16, 0, 0);
  }

  for (int k0 = kBeg; k0 < kEnd; k0 += 32) {
    const int p = (k0 >> 5) & 1;
    // own cur-tile loads complete (latency overlapped by previous step's MFMA)
    __builtin_amdgcn_s_waitcnt(0xF70);  // vmcnt(0), lgkm/exp don't-care
    __builtin_amdgcn_s_barrier();       // all waves' cur loads landed; buf[1-p] readers done
    // prefetch next tile into the other buffer; stays in flight through this step
    if (k0 + 32 < kEnd) {
#pragma unroll
      for (int j = 0; j < 2; ++j) {
        __builtin_amdgcn_global_load_lds(
            (const __attribute__((address_space(1))) uint32_t*)(gA[j] + k0 + 32),
            (__attribute__((address_space(3))) uint32_t*)(&lsA[p ^ 1][0] + ldsOff[j]), 16, 0, 0);
        __builtin_amdgcn_global_load_lds(
            (const __attribute__((address_space(1))) uint32_t*)(gB[j] + k0 + 32),
            (__attribute__((address_space(3))) uint32_t*)(&lsB[p ^ 1][0] + ldsOff[j]), 16, 0, 0);
      }
    }

    bf16x8 af[4], bf[4];
#pragma unroll
    for (int rt = 0; rt < 4; ++rt)
      af[rt] = *(const bf16x8*)(&lsA[p][0] + (q * 128 + wr * 64 + rt * 16 + mr) * 8);
#pragma unroll
    for (int ct = 0; ct < 4; ++ct)
      bf[ct] = *(const bf16x8*)(&lsB[p][0] + (q * 128 + wc * 64 + ct * 16 + mr) * 8);
#pragma unroll
    for (int rt = 0; rt < 4; ++rt)
#pragma unroll
      for (int ct = 0; ct < 4; ++ct)
        acc[rt][ct] = __builtin_amdgcn_mfma_f32_16x16x32_bf16(af[rt], bf[ct], acc[rt][ct], 0, 0, 0);
  }

  uint16_t* Dp = D + (size_t)ks * PSTRIDE;
  // epilogue: C/D layout col=lane&15, row=(lane>>4)*4+reg
#pragma unroll
  for (int rt = 0; rt < 4; ++rt) {
#pragma unroll
    for (int r = 0; r < 4; ++r) {
      int rowg = rowBase + wr * 64 + rt * 16 + (lane >> 4) * 4 + r;
      int b = rowg / CPB, c = rowg - b * CPB;
      int jj;
      if (MODE == 1) jj = (c < 2) ? (2 * s + c) : (4 + 16 * s + (c - 2));
      else jj = 16 * s + c;
      uint16_t* drow = Dp + (size_t)(b * OUTC + jj) * NNODE;
#pragma unroll
      for (int ct = 0; ct < 4; ++ct) {
        int colg = colBase + wc * 64 + ct * 16 + mr;
        drow[colg] = f2b(acc[rt][ct][r]);
      }
    }
  }
}

// ---------- stage2: r,u gates; X2 = r*prev (bf16), U kept fp32 ----------
__global__ __launch_bounds__(256) void stage2(
    const uint16_t* __restrict__ P1, const float* __restrict__ state,
    const float* __restrict__ rk, const float* __restrict__ uk,
    uint16_t* __restrict__ X2, float* __restrict__ U) {
  constexpr size_t PS = (size_t)64 * 36 * NNODE;
  __shared__ float s_rk[576], s_uk[576];
  for (int i = threadIdx.x; i < 576; i += 256) { s_rk[i] = rk[i]; s_uk[i] = uk[i]; }
  __syncthreads();
  int idx = blockIdx.x * 256 + threadIdx.x;
  int b = idx >> 12, n = idx & 4095;
  float hs[36];
  const uint16_t* p = P1 + (size_t)b * 36 * NNODE + n;
#pragma unroll
  for (int j = 0; j < 36; ++j)
    hs[j] = b2f(p[(size_t)j * NNODE]) + b2f(p[PS + (size_t)j * NNODE]);
  float ar[16], au[16];
#pragma unroll
  for (int k = 0; k < 16; ++k) { ar[k] = 0.f; au[k] = 0.f; }
#pragma unroll
  for (int j = 0; j < 36; ++j) {
    float h = hs[j];
#pragma unroll
    for (int k = 0; k < 16; ++k) {
      ar[k] += h * s_rk[j * 16 + k];
      au[k] += h * s_uk[j * 16 + k];
    }
  }
  const float* sp = state + (size_t)b * 65536 + n;
#pragma unroll
  for (int k = 0; k < 16; ++k) {
    float r = 1.f / (1.f + __expf(-ar[k]));
    float uu = 1.f / (1.f + __expf(-au[k]));
    float prev = sp[(size_t)k * NNODE];
    X2[(size_t)(b * 16 + k) * NNODE + n] = f2b(r * prev);
    U[(size_t)(b * 16 + k) * NNODE + n] = uu;
  }
}

// ---------- stage4: c = tanh([h;D3]*ck); z = u*prev + (1-u)*c ----------
// OUTPUT LAYOUT: z is (B, N, U) reshaped to (B, U*N) => out[b*65536 + n*16 + k]
__global__ __launch_bounds__(256) void stage4(
    const uint16_t* __restrict__ P1, const uint16_t* __restrict__ P3,
    const float* __restrict__ U, const float* __restrict__ state,
    const float* __restrict__ ck, float* __restrict__ out) {
  constexpr size_t PS1 = (size_t)64 * 36 * NNODE;
  constexpr size_t PS3 = (size_t)64 * 32 * NNODE;
  __shared__ float s_ck[576];
  for (int i = threadIdx.x; i < 576; i += 256) s_ck[i] = ck[i];
  __syncthreads();
  int idx = blockIdx.x * 256 + threadIdx.x;
  int b = idx >> 12, n = idx & 4095;
  float hv[36];
  const uint16_t* p1 = P1 + (size_t)b * 36 * NNODE + n;
#pragma unroll
  for (int j = 0; j < 4; ++j)
    hv[j] = b2f(p1[(size_t)j * NNODE]) + b2f(p1[PS1 + (size_t)j * NNODE]);
  const uint16_t* p3 = P3 + (size_t)b * 32 * NNODE + n;
#pragma unroll
  for (int j = 0; j < 32; ++j)
    hv[4 + j] = b2f(p3[(size_t)j * NNODE]) + b2f(p3[PS3 + (size_t)j * NNODE]);
  float ac[16];
#pragma unroll
  for (int k = 0; k < 16; ++k) ac[k] = 0.f;
#pragma unroll
  for (int j = 0; j < 36; ++j) {
    float h = hv[j];
#pragma unroll
    for (int k = 0; k < 16; ++k) ac[k] += h * s_ck[j * 16 + k];
  }
  const float* sp = state + (size_t)b * 65536 + n;
  const float* up = U + (size_t)b * 16 * NNODE + n;
  float z[16];
#pragma unroll
  for (int k = 0; k < 16; ++k) {
    float e = __expf(2.f * ac[k]);
    float c = 1.f - 2.f / (e + 1.f);  // tanh, saturates correctly at +/-inf
    float uu = up[(size_t)k * NNODE];
    float prev = sp[(size_t)k * NNODE];
    z[k] = uu * prev + (1.f - uu) * c;
  }
  float4* po = (float4*)(out + (size_t)b * 65536 + (size_t)n * 16);
#pragma unroll
  for (int k4 = 0; k4 < 4; ++k4)
    po[k4] = make_float4(z[k4 * 4], z[k4 * 4 + 1], z[k4 * 4 + 2], z[k4 * 4 + 3]);
}

extern "C" void kernel_launch(void* const* d_in, const int* in_sizes, int n_in,
                              void* d_out, int out_size, void* d_ws, size_t ws_size,
                              hipStream_t stream) {
  const float* inputs = (const float*)d_in[0];
  const float* state = (const float*)d_in[1];
  const float* s0 = (const float*)d_in[2];
  const float* s1 = (const float*)d_in[3];
  const float* rk = (const float*)d_in[4];
  const float* uk = (const float*)d_in[5];
  const float* ck = (const float*)d_in[6];
  float* out = (float*)d_out;
  char* ws = (char*)d_ws;

  // workspace layout (bytes); X2 aliases X1 (dead after gemm1)
  uint16_t* S0b = (uint16_t*)(ws);                  // 33,554,432
  uint16_t* S1b = (uint16_t*)(ws + 33554432);       // 33,554,432
  uint16_t* X1 = (uint16_t*)(ws + 67108864);        // 9,437,184   (1152 x 4096 bf16)
  uint16_t* X2 = (uint16_t*)(ws + 67108864);        // 8,388,608   (aliases X1)
  uint16_t* P1 = (uint16_t*)(ws + 76546048);        // 2 x 18,874,368 (split-K partials)
  float* U = (float*)(ws + 114294784);              // 16,777,216  (64 x 16 x 4096 f32)
  uint16_t* P3 = (uint16_t*)(ws + 131072000);       // 2 x 16,777,216 (split-K partials)
  // total 164,626,432 bytes

  cvt_supports<<<dim3(16384, 2), 256, 0, stream>>>(s0, s1, S0b, S1b);
  pack_x1<<<4608, 256, 0, stream>>>(inputs, state, X1);
  gemm_bt<1><<<dim3(32, 9, 2 * KSPLIT), 256, 0, stream>>>(X1, S0b, S1b, P1);
  stage2<<<1024, 256, 0, stream>>>(P1, state, rk, uk, X2, U);
  gemm_bt<3><<<dim3(32, 8, 2 * KSPLIT), 256, 0, stream>>>(X2, S0b, S1b, P3);
  stage4<<<1024, 256, 0, stream>>>(P1, P3, U, state, ck, out);
}